// Round 1
// baseline (545.401 us; speedup 1.0000x reference)
//
#include <hip/hip_runtime.h>

#define N_NODES 50000
#define H_DIM 96
#define EPS 1e-5f

// ---------------- CSR build ----------------

__global__ void deg_kernel(const int* __restrict__ dst, int* __restrict__ deg, int E) {
    int e = blockIdx.x * 256 + threadIdx.x;
    if (e < E) atomicAdd(&deg[dst[e]], 1);
}

__global__ void scan_kernel(const int* __restrict__ deg, int* __restrict__ rowptr, int n) {
    __shared__ int sums[1024];
    int t = threadIdx.x;
    int chunk = (n + 1023) >> 10;
    int s = t * chunk;
    int e = min(s + chunk, n);
    int local = 0;
    for (int i = s; i < e; ++i) local += deg[i];
    sums[t] = local;
    __syncthreads();
    for (int off = 1; off < 1024; off <<= 1) {
        int v = (t >= off) ? sums[t - off] : 0;
        __syncthreads();
        sums[t] += v;
        __syncthreads();
    }
    int prefix = (t > 0) ? sums[t - 1] : 0;
    for (int i = s; i < e; ++i) { rowptr[i] = prefix; prefix += deg[i]; }
    if (t == 1023) rowptr[n] = sums[1023];
}

__global__ void dinv_kernel(const int* __restrict__ deg, float* __restrict__ dinv, int n) {
    int i = blockIdx.x * 256 + threadIdx.x;
    if (i < n) dinv[i] = rsqrtf((float)(deg[i] + 1));   // +1 = self loop
}

__global__ void fill_kernel(const int* __restrict__ src, const int* __restrict__ dst,
                            const int* __restrict__ rowptr, int* __restrict__ cursor,
                            int* __restrict__ col, int E) {
    int e = blockIdx.x * 256 + threadIdx.x;
    if (e < E) {
        int d = dst[e];
        int pos = rowptr[d] + atomicAdd(&cursor[d], 1);
        col[pos] = src[e];
    }
}

// ---------------- dense GEMM: H = X @ W  (X: [N,CIN], W: [CIN,96]) ----------------

template <int CIN>
__global__ __launch_bounds__(256) void gemm_kernel(const float* __restrict__ X,
                                                   const float* __restrict__ W,
                                                   float* __restrict__ Hout, int N) {
    __shared__ float xs[64][32];
    __shared__ float ws[32][96];
    int tid = threadIdx.x;
    int tx = tid & 31;        // col group
    int ty = tid >> 5;        // 0..7, row group
    int rowbase = blockIdx.x * 64;

    float acc[8][3];
#pragma unroll
    for (int r = 0; r < 8; ++r)
#pragma unroll
        for (int j = 0; j < 3; ++j) acc[r][j] = 0.f;

    for (int kt = 0; kt < CIN; kt += 32) {
        // stage X tile: 64 rows x 32 k = 512 float4
#pragma unroll
        for (int f = tid; f < 512; f += 256) {
            int r = f >> 3, k4 = f & 7;
            int row = rowbase + r;
            float4 v = make_float4(0.f, 0.f, 0.f, 0.f);
            if (row < N) v = *reinterpret_cast<const float4*>(X + (size_t)row * CIN + kt + k4 * 4);
            *reinterpret_cast<float4*>(&xs[r][k4 * 4]) = v;
        }
        // stage W tile: 32 k x 96 c = 768 float4
#pragma unroll
        for (int f = tid; f < 768; f += 256) {
            int kk = f / 24, c4 = f % 24;
            float4 v = *reinterpret_cast<const float4*>(W + (size_t)(kt + kk) * 96 + c4 * 4);
            *reinterpret_cast<float4*>(&ws[kk][c4 * 4]) = v;
        }
        __syncthreads();
#pragma unroll
        for (int kk = 0; kk < 32; ++kk) {
            float w0 = ws[kk][tx], w1 = ws[kk][tx + 32], w2 = ws[kk][tx + 64];
#pragma unroll
            for (int r = 0; r < 8; ++r) {
                float xv = xs[ty * 8 + r][kk];
                acc[r][0] = fmaf(xv, w0, acc[r][0]);
                acc[r][1] = fmaf(xv, w1, acc[r][1]);
                acc[r][2] = fmaf(xv, w2, acc[r][2]);
            }
        }
        __syncthreads();
    }
#pragma unroll
    for (int r = 0; r < 8; ++r) {
        int row = rowbase + ty * 8 + r;
        if (row < N) {
            float* o = Hout + (size_t)row * 96;
            o[tx] = acc[r][0];
            o[tx + 32] = acc[r][1];
            o[tx + 64] = acc[r][2];
        }
    }
}

// ---------- fused: aggregate (sym-norm) + bias + LayerNorm + PReLU ----------
// 128 lanes per node (2 nodes per 256-block); lane = channel, 96 active.

__global__ __launch_bounds__(256) void agg_ln_prelu(const float* __restrict__ H,
                                                    const float* __restrict__ dinv,
                                                    const int* __restrict__ rowptr,
                                                    const int* __restrict__ col,
                                                    const float* __restrict__ bias,
                                                    const float* __restrict__ gamma,
                                                    const float* __restrict__ beta,
                                                    const float* __restrict__ alpha,
                                                    float* __restrict__ out, int N) {
    __shared__ float red[4][2];
    int tid = threadIdx.x;
    int sub = tid >> 7;          // node within block
    int c = tid & 127;           // channel lane
    int cc = min(c, 95);
    int node = blockIdx.x * 2 + sub;

    float acc = 0.f;
    if (node < N) {
        float di = dinv[node];
        acc = H[(size_t)node * 96 + cc] * di;                 // self loop (pre-scaled by di)
        int e0 = rowptr[node], e1 = rowptr[node + 1];
        for (int e = e0; e < e1; ++e) {
            int j = col[e];
            float dj = dinv[j];
            acc = fmaf(H[(size_t)j * 96 + cc], dj, acc);
        }
        acc = acc * di + bias[cc];
    }

    // LayerNorm over 96 channels of this node (lanes 96..127 contribute 0)
    float v = (c < 96 && node < N) ? acc : 0.f;
    float s1 = v, s2 = v * v;
#pragma unroll
    for (int o = 32; o > 0; o >>= 1) {
        s1 += __shfl_xor(s1, o);
        s2 += __shfl_xor(s2, o);
    }
    int w = tid >> 6;
    if ((tid & 63) == 0) { red[w][0] = s1; red[w][1] = s2; }
    __syncthreads();
    int wb = sub * 2;
    float sum = red[wb][0] + red[wb + 1][0];
    float sumsq = red[wb][1] + red[wb + 1][1];

    if (node < N && c < 96) {
        float mu = sum * (1.f / 96.f);
        float var = sumsq * (1.f / 96.f) - mu * mu;
        float rstd = rsqrtf(var + EPS);
        float ln = (acc - mu) * rstd * gamma[c] + beta[c];
        out[(size_t)node * 96 + c] = (ln >= 0.f) ? ln : alpha[c] * ln;
    }
}

// ---------------- launch ----------------

extern "C" void kernel_launch(void* const* d_in, const int* in_sizes, int n_in,
                              void* d_out, int out_size, void* d_ws, size_t ws_size,
                              hipStream_t stream) {
    const float* x   = (const float*)d_in[0];
    const int*   ei  = (const int*)d_in[1];
    const float* W1  = (const float*)d_in[2];
    const float* b1  = (const float*)d_in[3];
    const float* W2  = (const float*)d_in[4];
    const float* b2  = (const float*)d_in[5];
    const float* g1  = (const float*)d_in[6];
    const float* be1 = (const float*)d_in[7];
    const float* g2  = (const float*)d_in[8];
    const float* be2 = (const float*)d_in[9];
    const float* a   = (const float*)d_in[10];

    const int N = in_sizes[0] / 128;       // 50000
    const int E = in_sizes[1] / 2;         // 800000
    const int* src = ei;
    const int* dst = ei + E;

    char* ws = (char*)d_ws;
    size_t off = 0;
    auto carve = [&](size_t bytes) -> void* {
        void* p = ws + off;
        off += (bytes + 255) & ~(size_t)255;
        return p;
    };
    int*   deg    = (int*)carve((size_t)N * 4);
    int*   cursor = (int*)carve((size_t)N * 4);
    int*   rowptr = (int*)carve((size_t)(N + 1) * 4);
    float* dinv   = (float*)carve((size_t)N * 4);
    int*   col    = (int*)carve((size_t)E * 4);
    float* hbuf   = (float*)carve((size_t)N * 96 * 4);
    float* p1     = (float*)d_out;   // reuse output buffer as layer-1 activation
    float* outp   = (float*)d_out;

    hipMemsetAsync(deg, 0, (size_t)N * 4, stream);
    hipMemsetAsync(cursor, 0, (size_t)N * 4, stream);

    deg_kernel<<<(E + 255) / 256, 256, 0, stream>>>(dst, deg, E);
    scan_kernel<<<1, 1024, 0, stream>>>(deg, rowptr, N);
    dinv_kernel<<<(N + 255) / 256, 256, 0, stream>>>(deg, dinv, N);
    fill_kernel<<<(E + 255) / 256, 256, 0, stream>>>(src, dst, rowptr, cursor, col, E);

    // layer 1
    gemm_kernel<128><<<(N + 63) / 64, 256, 0, stream>>>(x, W1, hbuf, N);
    agg_ln_prelu<<<(N + 1) / 2, 256, 0, stream>>>(hbuf, dinv, rowptr, col, b1, g1, be1, a, p1, N);
    // layer 2
    gemm_kernel<96><<<(N + 63) / 64, 256, 0, stream>>>(p1, W2, hbuf, N);
    agg_ln_prelu<<<(N + 1) / 2, 256, 0, stream>>>(hbuf, dinv, rowptr, col, b2, g2, be2, a, outp, N);
}

// Round 2
// 393.297 us; speedup vs baseline: 1.3867x; 1.3867x over previous
//
#include <hip/hip_runtime.h>

#define N_NODES 50000
#define H_DIM 96
#define EPS 1e-5f

// ---------------- CSR build ----------------

__global__ void deg_kernel(const int* __restrict__ dst, int* __restrict__ deg, int E) {
    int e = blockIdx.x * 256 + threadIdx.x;
    if (e < E) atomicAdd(&deg[dst[e]], 1);
}

__global__ void scan_kernel(const int* __restrict__ deg, int* __restrict__ rowptr, int n) {
    __shared__ int sums[1024];
    int t = threadIdx.x;
    int chunk = (n + 1023) >> 10;
    int s = t * chunk;
    int e = min(s + chunk, n);
    int local = 0;
    for (int i = s; i < e; ++i) local += deg[i];
    sums[t] = local;
    __syncthreads();
    for (int off = 1; off < 1024; off <<= 1) {
        int v = (t >= off) ? sums[t - off] : 0;
        __syncthreads();
        sums[t] += v;
        __syncthreads();
    }
    int prefix = (t > 0) ? sums[t - 1] : 0;
    for (int i = s; i < e; ++i) { rowptr[i] = prefix; prefix += deg[i]; }
    if (t == 1023) rowptr[n] = sums[1023];
}

__global__ void dinv_kernel(const int* __restrict__ deg, float* __restrict__ dinv, int n) {
    int i = blockIdx.x * 256 + threadIdx.x;
    if (i < n) dinv[i] = rsqrtf((float)(deg[i] + 1));   // +1 = self loop
}

__global__ void fill_kernel(const int* __restrict__ src, const int* __restrict__ dst,
                            const int* __restrict__ rowptr, int* __restrict__ cursor,
                            int* __restrict__ col, int E) {
    int e = blockIdx.x * 256 + threadIdx.x;
    if (e < E) {
        int d = dst[e];
        int pos = rowptr[d] + atomicAdd(&cursor[d], 1);
        col[pos] = src[e];
    }
}

// ---- dense GEMM with fused dinv prescale: Hs = (X @ W) * dinv[row] ----

template <int CIN>
__global__ __launch_bounds__(256) void gemm_kernel(const float* __restrict__ X,
                                                   const float* __restrict__ W,
                                                   const float* __restrict__ dinv,
                                                   float* __restrict__ Hout, int N) {
    __shared__ float xs[64][32];
    __shared__ float ws[32][96];
    int tid = threadIdx.x;
    int tx = tid & 31;        // col group
    int ty = tid >> 5;        // 0..7, row group
    int rowbase = blockIdx.x * 64;

    float acc[8][3];
#pragma unroll
    for (int r = 0; r < 8; ++r)
#pragma unroll
        for (int j = 0; j < 3; ++j) acc[r][j] = 0.f;

    for (int kt = 0; kt < CIN; kt += 32) {
        // stage X tile: 64 rows x 32 k = 512 float4
#pragma unroll
        for (int f = tid; f < 512; f += 256) {
            int r = f >> 3, k4 = f & 7;
            int row = rowbase + r;
            float4 v = make_float4(0.f, 0.f, 0.f, 0.f);
            if (row < N) v = *reinterpret_cast<const float4*>(X + (size_t)row * CIN + kt + k4 * 4);
            *reinterpret_cast<float4*>(&xs[r][k4 * 4]) = v;
        }
        // stage W tile: 32 k x 96 c = 768 float4
#pragma unroll
        for (int f = tid; f < 768; f += 256) {
            int kk = f / 24, c4 = f % 24;
            float4 v = *reinterpret_cast<const float4*>(W + (size_t)(kt + kk) * 96 + c4 * 4);
            *reinterpret_cast<float4*>(&ws[kk][c4 * 4]) = v;
        }
        __syncthreads();
#pragma unroll
        for (int kk = 0; kk < 32; ++kk) {
            float w0 = ws[kk][tx], w1 = ws[kk][tx + 32], w2 = ws[kk][tx + 64];
#pragma unroll
            for (int r = 0; r < 8; ++r) {
                float xv = xs[ty * 8 + r][kk];
                acc[r][0] = fmaf(xv, w0, acc[r][0]);
                acc[r][1] = fmaf(xv, w1, acc[r][1]);
                acc[r][2] = fmaf(xv, w2, acc[r][2]);
            }
        }
        __syncthreads();
    }
#pragma unroll
    for (int r = 0; r < 8; ++r) {
        int row = rowbase + ty * 8 + r;
        if (row < N) {
            float di = dinv[row];
            float* o = Hout + (size_t)row * 96;
            o[tx]      = acc[r][0] * di;
            o[tx + 32] = acc[r][1] * di;
            o[tx + 64] = acc[r][2] * di;
        }
    }
}

// ---------- fused: aggregate (sym-norm) + bias + LayerNorm + PReLU ----------
// Hs rows are pre-scaled by dinv[row]. out[i] = di*(Hs[i] + sum_j Hs[j]) + bias,
// then LayerNorm + PReLU. 128 lanes per node, lane = channel (96 active).

__global__ __launch_bounds__(256) void agg_ln_prelu(const float* __restrict__ Hs,
                                                    const float* __restrict__ dinv,
                                                    const int* __restrict__ rowptr,
                                                    const int* __restrict__ col,
                                                    const float* __restrict__ bias,
                                                    const float* __restrict__ gamma,
                                                    const float* __restrict__ beta,
                                                    const float* __restrict__ alpha,
                                                    float* __restrict__ out, int N) {
    __shared__ float red[4][2];
    int tid = threadIdx.x;
    int sub = tid >> 7;          // node within block
    int c = tid & 127;           // channel lane
    int cc = min(c, 95);
    int node = blockIdx.x * 2 + sub;

    float acc = 0.f;
    if (node < N) {
        float a0 = Hs[(size_t)node * 96 + cc];   // self loop (pre-scaled)
        float a1 = 0.f, a2 = 0.f, a3 = 0.f;
        int e0 = rowptr[node], e1 = rowptr[node + 1];
        int e = e0;
        // 8-wide unroll: 8 independent index loads, then 8 independent gathers
        for (; e + 8 <= e1; e += 8) {
            int j0 = col[e],     j1 = col[e + 1], j2 = col[e + 2], j3 = col[e + 3];
            int j4 = col[e + 4], j5 = col[e + 5], j6 = col[e + 6], j7 = col[e + 7];
            float v0 = Hs[(size_t)j0 * 96 + cc];
            float v1 = Hs[(size_t)j1 * 96 + cc];
            float v2 = Hs[(size_t)j2 * 96 + cc];
            float v3 = Hs[(size_t)j3 * 96 + cc];
            float v4 = Hs[(size_t)j4 * 96 + cc];
            float v5 = Hs[(size_t)j5 * 96 + cc];
            float v6 = Hs[(size_t)j6 * 96 + cc];
            float v7 = Hs[(size_t)j7 * 96 + cc];
            a0 += v0; a1 += v1; a2 += v2; a3 += v3;
            a0 += v4; a1 += v5; a2 += v6; a3 += v7;
        }
        for (; e < e1; ++e) {
            int j = col[e];
            a1 += Hs[(size_t)j * 96 + cc];
        }
        float di = dinv[node];
        acc = ((a0 + a1) + (a2 + a3)) * di + bias[cc];
    }

    // LayerNorm over 96 channels of this node (lanes 96..127 contribute 0)
    float v = (c < 96 && node < N) ? acc : 0.f;
    float s1 = v, s2 = v * v;
#pragma unroll
    for (int o = 32; o > 0; o >>= 1) {
        s1 += __shfl_xor(s1, o);
        s2 += __shfl_xor(s2, o);
    }
    int w = tid >> 6;
    if ((tid & 63) == 0) { red[w][0] = s1; red[w][1] = s2; }
    __syncthreads();
    int wb = sub * 2;
    float sum = red[wb][0] + red[wb + 1][0];
    float sumsq = red[wb][1] + red[wb + 1][1];

    if (node < N && c < 96) {
        float mu = sum * (1.f / 96.f);
        float var = sumsq * (1.f / 96.f) - mu * mu;
        float rstd = rsqrtf(var + EPS);
        float ln = (acc - mu) * rstd * gamma[c] + beta[c];
        out[(size_t)node * 96 + c] = (ln >= 0.f) ? ln : alpha[c] * ln;
    }
}

// ---------------- launch ----------------

extern "C" void kernel_launch(void* const* d_in, const int* in_sizes, int n_in,
                              void* d_out, int out_size, void* d_ws, size_t ws_size,
                              hipStream_t stream) {
    const float* x   = (const float*)d_in[0];
    const int*   ei  = (const int*)d_in[1];
    const float* W1  = (const float*)d_in[2];
    const float* b1  = (const float*)d_in[3];
    const float* W2  = (const float*)d_in[4];
    const float* b2  = (const float*)d_in[5];
    const float* g1  = (const float*)d_in[6];
    const float* be1 = (const float*)d_in[7];
    const float* g2  = (const float*)d_in[8];
    const float* be2 = (const float*)d_in[9];
    const float* a   = (const float*)d_in[10];

    const int N = in_sizes[0] / 128;       // 50000
    const int E = in_sizes[1] / 2;         // 800000
    const int* src = ei;
    const int* dst = ei + E;

    char* ws = (char*)d_ws;
    size_t off = 0;
    auto carve = [&](size_t bytes) -> void* {
        void* p = ws + off;
        off += (bytes + 255) & ~(size_t)255;
        return p;
    };
    int*   deg    = (int*)carve((size_t)N * 4);
    int*   cursor = (int*)carve((size_t)N * 4);
    int*   rowptr = (int*)carve((size_t)(N + 1) * 4);
    float* dinv   = (float*)carve((size_t)N * 4);
    int*   col    = (int*)carve((size_t)E * 4);
    float* hbuf   = (float*)carve((size_t)N * 96 * 4);
    float* p1     = (float*)d_out;   // reuse output buffer as layer-1 activation
    float* outp   = (float*)d_out;

    hipMemsetAsync(deg, 0, (size_t)N * 4, stream);
    hipMemsetAsync(cursor, 0, (size_t)N * 4, stream);

    deg_kernel<<<(E + 255) / 256, 256, 0, stream>>>(dst, deg, E);
    scan_kernel<<<1, 1024, 0, stream>>>(deg, rowptr, N);
    dinv_kernel<<<(N + 255) / 256, 256, 0, stream>>>(deg, dinv, N);
    fill_kernel<<<(E + 255) / 256, 256, 0, stream>>>(src, dst, rowptr, cursor, col, E);

    // layer 1
    gemm_kernel<128><<<(N + 63) / 64, 256, 0, stream>>>(x, W1, dinv, hbuf, N);
    agg_ln_prelu<<<(N + 1) / 2, 256, 0, stream>>>(hbuf, dinv, rowptr, col, b1, g1, be1, a, p1, N);
    // layer 2
    gemm_kernel<96><<<(N + 63) / 64, 256, 0, stream>>>(p1, W2, dinv, hbuf, N);
    agg_ln_prelu<<<(N + 1) / 2, 256, 0, stream>>>(hbuf, dinv, rowptr, col, b2, g2, be2, a, outp, N);
}

// Round 3
// 325.365 us; speedup vs baseline: 1.6763x; 1.2088x over previous
//
#include <hip/hip_runtime.h>

#define N_NODES 50000
#define H_DIM 96
#define EPS 1e-5f

typedef unsigned int uint32;

// ---------------- CSR build ----------------

__global__ void deg_kernel(const int* __restrict__ dst, int* __restrict__ deg, int E) {
    int e = blockIdx.x * 256 + threadIdx.x;
    if (e < E) atomicAdd(&deg[dst[e]], 1);
}

__global__ void scan_kernel(const int* __restrict__ deg, int* __restrict__ rowptr, int n) {
    __shared__ int sums[1024];
    int t = threadIdx.x;
    int chunk = (n + 1023) >> 10;
    int s = t * chunk;
    int e = min(s + chunk, n);
    int local = 0;
    for (int i = s; i < e; ++i) local += deg[i];
    sums[t] = local;
    __syncthreads();
    for (int off = 1; off < 1024; off <<= 1) {
        int v = (t >= off) ? sums[t - off] : 0;
        __syncthreads();
        sums[t] += v;
        __syncthreads();
    }
    int prefix = (t > 0) ? sums[t - 1] : 0;
    for (int i = s; i < e; ++i) { rowptr[i] = prefix; prefix += deg[i]; }
    if (t == 1023) rowptr[n] = sums[1023];
}

__global__ void dinv_kernel(const int* __restrict__ deg, float* __restrict__ dinv, int n) {
    int i = blockIdx.x * 256 + threadIdx.x;
    if (i < n) dinv[i] = rsqrtf((float)(deg[i] + 1));   // +1 = self loop
}

__global__ void fill_kernel(const int* __restrict__ src, const int* __restrict__ dst,
                            const int* __restrict__ rowptr, int* __restrict__ cursor,
                            int* __restrict__ col, int E) {
    int e = blockIdx.x * 256 + threadIdx.x;
    if (e < E) {
        int d = dst[e];
        int pos = rowptr[d] + atomicAdd(&cursor[d], 1);
        col[pos] = src[e];
    }
}

// ---- bf16 pack helper (RNE) ----
__device__ __forceinline__ uint32 bf16_rne(float f) {
    uint32 b = __float_as_uint(f);
    return (b + 0x7fffu + ((b >> 16) & 1u)) >> 16;
}

// ---- dense GEMM, epilogue: Hs[row] = bf16x2-packed (X@W)[row] * dinv[row] ----
// Hs layout: N rows x 48 uint32 (channel pairs (0,1),(2,3),...)

template <int CIN>
__global__ __launch_bounds__(256) void gemm_kernel(const float* __restrict__ X,
                                                   const float* __restrict__ W,
                                                   const float* __restrict__ dinv,
                                                   uint32* __restrict__ Hs, int N) {
    __shared__ float xs[64][32];
    __shared__ float ws[32][96];
    int tid = threadIdx.x;
    int tx = tid & 31;        // col group
    int ty = tid >> 5;        // 0..7, row group
    int rowbase = blockIdx.x * 64;

    float acc[8][3];
#pragma unroll
    for (int r = 0; r < 8; ++r)
#pragma unroll
        for (int j = 0; j < 3; ++j) acc[r][j] = 0.f;

    for (int kt = 0; kt < CIN; kt += 32) {
#pragma unroll
        for (int f = tid; f < 512; f += 256) {
            int r = f >> 3, k4 = f & 7;
            int row = rowbase + r;
            float4 v = make_float4(0.f, 0.f, 0.f, 0.f);
            if (row < N) v = *reinterpret_cast<const float4*>(X + (size_t)row * CIN + kt + k4 * 4);
            *reinterpret_cast<float4*>(&xs[r][k4 * 4]) = v;
        }
#pragma unroll
        for (int f = tid; f < 768; f += 256) {
            int kk = f / 24, c4 = f % 24;
            float4 v = *reinterpret_cast<const float4*>(W + (size_t)(kt + kk) * 96 + c4 * 4);
            *reinterpret_cast<float4*>(&ws[kk][c4 * 4]) = v;
        }
        __syncthreads();
#pragma unroll
        for (int kk = 0; kk < 32; ++kk) {
            float w0 = ws[kk][tx], w1 = ws[kk][tx + 32], w2 = ws[kk][tx + 64];
#pragma unroll
            for (int r = 0; r < 8; ++r) {
                float xv = xs[ty * 8 + r][kk];
                acc[r][0] = fmaf(xv, w0, acc[r][0]);
                acc[r][1] = fmaf(xv, w1, acc[r][1]);
                acc[r][2] = fmaf(xv, w2, acc[r][2]);
            }
        }
        __syncthreads();
    }
#pragma unroll
    for (int r = 0; r < 8; ++r) {
        int row = rowbase + ty * 8 + r;
        float di = (row < N) ? dinv[row] : 0.f;
#pragma unroll
        for (int j = 0; j < 3; ++j) {
            float v = acc[r][j] * di;
            float vp = __shfl_xor(v, 1);        // partner channel
            if (row < N && !(tx & 1)) {
                int cpair = (tx + 32 * j) >> 1; // channel pair index 0..47
                Hs[(size_t)row * 48 + cpair] = bf16_rne(v) | (bf16_rne(vp) << 16);
            }
        }
    }
}

// ---------- fused: aggregate (sym-norm) + bias + LayerNorm + PReLU ----------
// One wave (64 lanes) per node; lanes 0..47 each own 2 channels (bf16x2).
// Hs rows pre-scaled by dinv. out[i] = di*(Hs[i] + sum_j Hs[j]) + bias -> LN -> PReLU.

__global__ __launch_bounds__(256) void agg_ln_prelu(const uint32* __restrict__ Hs,
                                                    const float* __restrict__ dinv,
                                                    const int* __restrict__ rowptr,
                                                    const int* __restrict__ col,
                                                    const float* __restrict__ bias,
                                                    const float* __restrict__ gamma,
                                                    const float* __restrict__ beta,
                                                    const float* __restrict__ alpha,
                                                    float* __restrict__ out, int N) {
    int lane = threadIdx.x & 63;
    int node = blockIdx.x * 4 + (threadIdx.x >> 6);
    if (node >= N) return;

    bool active = lane < 48;
    float c0 = 0.f, c1 = 0.f;

    if (active) {
        const uint32* row = Hs + (size_t)node * 48 + lane;
        uint32 u = *row;
        float a0 = __uint_as_float(u << 16), a1 = __uint_as_float(u & 0xffff0000u);
        float b0 = 0.f, b1 = 0.f, d0 = 0.f, d1 = 0.f, f0 = 0.f, f1 = 0.f;
        int e0 = rowptr[node], e1 = rowptr[node + 1];
        int e = e0;
        for (; e + 8 <= e1; e += 8) {
            int j0 = col[e],     j1 = col[e + 1], j2 = col[e + 2], j3 = col[e + 3];
            int j4 = col[e + 4], j5 = col[e + 5], j6 = col[e + 6], j7 = col[e + 7];
            uint32 u0 = Hs[(size_t)j0 * 48 + lane];
            uint32 u1 = Hs[(size_t)j1 * 48 + lane];
            uint32 u2 = Hs[(size_t)j2 * 48 + lane];
            uint32 u3 = Hs[(size_t)j3 * 48 + lane];
            uint32 u4 = Hs[(size_t)j4 * 48 + lane];
            uint32 u5 = Hs[(size_t)j5 * 48 + lane];
            uint32 u6 = Hs[(size_t)j6 * 48 + lane];
            uint32 u7 = Hs[(size_t)j7 * 48 + lane];
            a0 += __uint_as_float(u0 << 16); a1 += __uint_as_float(u0 & 0xffff0000u);
            b0 += __uint_as_float(u1 << 16); b1 += __uint_as_float(u1 & 0xffff0000u);
            d0 += __uint_as_float(u2 << 16); d1 += __uint_as_float(u2 & 0xffff0000u);
            f0 += __uint_as_float(u3 << 16); f1 += __uint_as_float(u3 & 0xffff0000u);
            a0 += __uint_as_float(u4 << 16); a1 += __uint_as_float(u4 & 0xffff0000u);
            b0 += __uint_as_float(u5 << 16); b1 += __uint_as_float(u5 & 0xffff0000u);
            d0 += __uint_as_float(u6 << 16); d1 += __uint_as_float(u6 & 0xffff0000u);
            f0 += __uint_as_float(u7 << 16); f1 += __uint_as_float(u7 & 0xffff0000u);
        }
        for (; e < e1; ++e) {
            uint32 u0 = Hs[(size_t)col[e] * 48 + lane];
            b0 += __uint_as_float(u0 << 16); b1 += __uint_as_float(u0 & 0xffff0000u);
        }
        float di = dinv[node];
        float2 bs = *reinterpret_cast<const float2*>(bias + 2 * lane);
        c0 = ((a0 + b0) + (d0 + f0)) * di + bs.x;
        c1 = ((a1 + b1) + (d1 + f1)) * di + bs.y;
    }

    // LayerNorm over 96 channels: 64-lane butterfly (inactive lanes contribute 0)
    float s1 = c0 + c1;
    float s2 = c0 * c0 + c1 * c1;
#pragma unroll
    for (int o = 32; o > 0; o >>= 1) {
        s1 += __shfl_xor(s1, o);
        s2 += __shfl_xor(s2, o);
    }

    if (active) {
        float mu = s1 * (1.f / 96.f);
        float var = s2 * (1.f / 96.f) - mu * mu;
        float rstd = rsqrtf(var + EPS);
        float2 gm = *reinterpret_cast<const float2*>(gamma + 2 * lane);
        float2 bt = *reinterpret_cast<const float2*>(beta + 2 * lane);
        float2 al = *reinterpret_cast<const float2*>(alpha + 2 * lane);
        float ln0 = (c0 - mu) * rstd * gm.x + bt.x;
        float ln1 = (c1 - mu) * rstd * gm.y + bt.y;
        float2 o2;
        o2.x = (ln0 >= 0.f) ? ln0 : al.x * ln0;
        o2.y = (ln1 >= 0.f) ? ln1 : al.y * ln1;
        *reinterpret_cast<float2*>(out + (size_t)node * 96 + 2 * lane) = o2;
    }
}

// ---------------- launch ----------------

extern "C" void kernel_launch(void* const* d_in, const int* in_sizes, int n_in,
                              void* d_out, int out_size, void* d_ws, size_t ws_size,
                              hipStream_t stream) {
    const float* x   = (const float*)d_in[0];
    const int*   ei  = (const int*)d_in[1];
    const float* W1  = (const float*)d_in[2];
    const float* b1  = (const float*)d_in[3];
    const float* W2  = (const float*)d_in[4];
    const float* b2  = (const float*)d_in[5];
    const float* g1  = (const float*)d_in[6];
    const float* be1 = (const float*)d_in[7];
    const float* g2  = (const float*)d_in[8];
    const float* be2 = (const float*)d_in[9];
    const float* a   = (const float*)d_in[10];

    const int N = in_sizes[0] / 128;       // 50000
    const int E = in_sizes[1] / 2;         // 800000
    const int* src = ei;
    const int* dst = ei + E;

    char* ws = (char*)d_ws;
    size_t off = 0;
    auto carve = [&](size_t bytes) -> void* {
        void* p = ws + off;
        off += (bytes + 255) & ~(size_t)255;
        return p;
    };
    int*    deg    = (int*)carve((size_t)N * 4);
    int*    cursor = (int*)carve((size_t)N * 4);
    int*    rowptr = (int*)carve((size_t)(N + 1) * 4);
    float*  dinv   = (float*)carve((size_t)N * 4);
    int*    col    = (int*)carve((size_t)E * 4);
    uint32* hbuf   = (uint32*)carve((size_t)N * 48 * 4);   // bf16x2 table
    float*  p1     = (float*)d_out;   // layer-1 activation reuses output buffer
    float*  outp   = (float*)d_out;

    hipMemsetAsync(deg, 0, (size_t)N * 4, stream);
    hipMemsetAsync(cursor, 0, (size_t)N * 4, stream);

    deg_kernel<<<(E + 255) / 256, 256, 0, stream>>>(dst, deg, E);
    scan_kernel<<<1, 1024, 0, stream>>>(deg, rowptr, N);
    dinv_kernel<<<(N + 255) / 256, 256, 0, stream>>>(deg, dinv, N);
    fill_kernel<<<(E + 255) / 256, 256, 0, stream>>>(src, dst, rowptr, cursor, col, E);

    // layer 1
    gemm_kernel<128><<<(N + 63) / 64, 256, 0, stream>>>(x, W1, dinv, hbuf, N);
    agg_ln_prelu<<<(N + 3) / 4, 256, 0, stream>>>(hbuf, dinv, rowptr, col, b1, g1, be1, a, p1, N);
    // layer 2
    gemm_kernel<96><<<(N + 63) / 64, 256, 0, stream>>>(p1, W2, dinv, hbuf, N);
    agg_ln_prelu<<<(N + 3) / 4, 256, 0, stream>>>(hbuf, dinv, rowptr, col, b2, g2, be2, a, outp, N);
}

// Round 4
// 250.298 us; speedup vs baseline: 2.1790x; 1.2999x over previous
//
#include <hip/hip_runtime.h>

#define N_NODES 50000
#define H_DIM 96
#define EPS 1e-5f

typedef unsigned int uint32;

// ---------------- CSR build ----------------

__global__ void deg_kernel(const int* __restrict__ dst, int* __restrict__ deg, int E) {
    int e = blockIdx.x * 256 + threadIdx.x;
    if (e < E) atomicAdd(&deg[dst[e]], 1);
}

// stage 1: per-block exclusive scan + block sums (256 thr, 1 elem/thr)
__global__ __launch_bounds__(256) void scan_blocks(const int* __restrict__ deg,
                                                   int* __restrict__ partial,
                                                   int* __restrict__ bsum, int n) {
    __shared__ int wsum[4];
    int i = blockIdx.x * 256 + threadIdx.x;
    int lane = threadIdx.x & 63, w = threadIdx.x >> 6;
    int v = (i < n) ? deg[i] : 0;
    int s = v;
#pragma unroll
    for (int o = 1; o < 64; o <<= 1) { int t = __shfl_up(s, o); if (lane >= o) s += t; }
    if (lane == 63) wsum[w] = s;
    __syncthreads();
    int off = 0;
#pragma unroll
    for (int k = 0; k < 4; ++k) if (k < w) off += wsum[k];
    s += off;
    if (i < n) partial[i] = s - v;              // exclusive within block
    if (threadIdx.x == 255) bsum[blockIdx.x] = s;  // block total
}

// stage 2: single-block exclusive scan of block sums (nb <= 256)
__global__ __launch_bounds__(256) void scan_bsums(int* __restrict__ bsum, int nb) {
    __shared__ int wsum[4];
    int t = threadIdx.x;
    int lane = t & 63, w = t >> 6;
    int v = (t < nb) ? bsum[t] : 0;
    int s = v;
#pragma unroll
    for (int o = 1; o < 64; o <<= 1) { int tt = __shfl_up(s, o); if (lane >= o) s += tt; }
    if (lane == 63) wsum[w] = s;
    __syncthreads();
    int off = 0;
#pragma unroll
    for (int k = 0; k < 4; ++k) if (k < w) off += wsum[k];
    s += off;
    if (t < nb) bsum[t] = s - v;                // exclusive
}

// stage 3: rowptr = partial + block offset; fused dinv
__global__ __launch_bounds__(256) void finalize_kernel(const int* __restrict__ partial,
                                                       const int* __restrict__ bsum,
                                                       const int* __restrict__ deg,
                                                       int* __restrict__ rowptr,
                                                       float* __restrict__ dinv,
                                                       int n, int E) {
    int i = blockIdx.x * 256 + threadIdx.x;
    if (i < n) {
        rowptr[i] = partial[i] + bsum[blockIdx.x];
        dinv[i] = rsqrtf((float)(deg[i] + 1));  // +1 = self loop
    }
    if (i == 0) rowptr[n] = E;
}

__global__ void fill_kernel(const int* __restrict__ src, const int* __restrict__ dst,
                            const int* __restrict__ rowptr, int* __restrict__ cursor,
                            int* __restrict__ col, int E) {
    int e = blockIdx.x * 256 + threadIdx.x;
    if (e < E) {
        int d = dst[e];
        int pos = rowptr[d] + atomicAdd(&cursor[d], 1);
        col[pos] = src[e];
    }
}

// ---- bf16 pack helper (RNE) ----
__device__ __forceinline__ uint32 bf16_rne(float f) {
    uint32 b = __float_as_uint(f);
    return (b + 0x7fffu + ((b >> 16) & 1u)) >> 16;
}

// ---- dense GEMM, epilogue: Hs[row] = bf16x2-packed (X@W)[row] * dinv[row] ----
// Hs layout: N rows x 48 uint32 (channel pairs (0,1),(2,3),...)

template <int CIN>
__global__ __launch_bounds__(256) void gemm_kernel(const float* __restrict__ X,
                                                   const float* __restrict__ W,
                                                   const float* __restrict__ dinv,
                                                   uint32* __restrict__ Hs, int N) {
    __shared__ float xs[64][32];
    __shared__ float ws[32][96];
    int tid = threadIdx.x;
    int tx = tid & 31;        // col group
    int ty = tid >> 5;        // 0..7, row group
    int rowbase = blockIdx.x * 64;

    float acc[8][3];
#pragma unroll
    for (int r = 0; r < 8; ++r)
#pragma unroll
        for (int j = 0; j < 3; ++j) acc[r][j] = 0.f;

    for (int kt = 0; kt < CIN; kt += 32) {
#pragma unroll
        for (int f = tid; f < 512; f += 256) {
            int r = f >> 3, k4 = f & 7;
            int row = rowbase + r;
            float4 v = make_float4(0.f, 0.f, 0.f, 0.f);
            if (row < N) v = *reinterpret_cast<const float4*>(X + (size_t)row * CIN + kt + k4 * 4);
            *reinterpret_cast<float4*>(&xs[r][k4 * 4]) = v;
        }
#pragma unroll
        for (int f = tid; f < 768; f += 256) {
            int kk = f / 24, c4 = f % 24;
            float4 v = *reinterpret_cast<const float4*>(W + (size_t)(kt + kk) * 96 + c4 * 4);
            *reinterpret_cast<float4*>(&ws[kk][c4 * 4]) = v;
        }
        __syncthreads();
#pragma unroll
        for (int kk = 0; kk < 32; ++kk) {
            float w0 = ws[kk][tx], w1 = ws[kk][tx + 32], w2 = ws[kk][tx + 64];
#pragma unroll
            for (int r = 0; r < 8; ++r) {
                float xv = xs[ty * 8 + r][kk];
                acc[r][0] = fmaf(xv, w0, acc[r][0]);
                acc[r][1] = fmaf(xv, w1, acc[r][1]);
                acc[r][2] = fmaf(xv, w2, acc[r][2]);
            }
        }
        __syncthreads();
    }
#pragma unroll
    for (int r = 0; r < 8; ++r) {
        int row = rowbase + ty * 8 + r;
        float di = (row < N) ? dinv[row] : 0.f;
#pragma unroll
        for (int j = 0; j < 3; ++j) {
            float v = acc[r][j] * di;
            float vp = __shfl_xor(v, 1);        // partner channel
            if (row < N && !(tx & 1)) {
                int cpair = (tx + 32 * j) >> 1; // channel pair index 0..47
                Hs[(size_t)row * 48 + cpair] = bf16_rne(v) | (bf16_rne(vp) << 16);
            }
        }
    }
}

// ---------- fused: aggregate (sym-norm) + bias + LayerNorm + PReLU ----------
// One wave (64 lanes) per node; lanes 0..47 each own 2 channels (bf16x2).

__global__ __launch_bounds__(256) void agg_ln_prelu(const uint32* __restrict__ Hs,
                                                    const float* __restrict__ dinv,
                                                    const int* __restrict__ rowptr,
                                                    const int* __restrict__ col,
                                                    const float* __restrict__ bias,
                                                    const float* __restrict__ gamma,
                                                    const float* __restrict__ beta,
                                                    const float* __restrict__ alpha,
                                                    float* __restrict__ out, int N) {
    int lane = threadIdx.x & 63;
    int node = blockIdx.x * 4 + (threadIdx.x >> 6);
    if (node >= N) return;

    bool active = lane < 48;
    float c0 = 0.f, c1 = 0.f;

    if (active) {
        uint32 u = Hs[(size_t)node * 48 + lane];
        float a0 = __uint_as_float(u << 16), a1 = __uint_as_float(u & 0xffff0000u);
        float b0 = 0.f, b1 = 0.f, d0 = 0.f, d1 = 0.f, f0 = 0.f, f1 = 0.f;
        int e0 = rowptr[node], e1 = rowptr[node + 1];
        int e = e0;
        for (; e + 8 <= e1; e += 8) {
            int j0 = col[e],     j1 = col[e + 1], j2 = col[e + 2], j3 = col[e + 3];
            int j4 = col[e + 4], j5 = col[e + 5], j6 = col[e + 6], j7 = col[e + 7];
            uint32 u0 = Hs[(size_t)j0 * 48 + lane];
            uint32 u1 = Hs[(size_t)j1 * 48 + lane];
            uint32 u2 = Hs[(size_t)j2 * 48 + lane];
            uint32 u3 = Hs[(size_t)j3 * 48 + lane];
            uint32 u4 = Hs[(size_t)j4 * 48 + lane];
            uint32 u5 = Hs[(size_t)j5 * 48 + lane];
            uint32 u6 = Hs[(size_t)j6 * 48 + lane];
            uint32 u7 = Hs[(size_t)j7 * 48 + lane];
            a0 += __uint_as_float(u0 << 16); a1 += __uint_as_float(u0 & 0xffff0000u);
            b0 += __uint_as_float(u1 << 16); b1 += __uint_as_float(u1 & 0xffff0000u);
            d0 += __uint_as_float(u2 << 16); d1 += __uint_as_float(u2 & 0xffff0000u);
            f0 += __uint_as_float(u3 << 16); f1 += __uint_as_float(u3 & 0xffff0000u);
            a0 += __uint_as_float(u4 << 16); a1 += __uint_as_float(u4 & 0xffff0000u);
            b0 += __uint_as_float(u5 << 16); b1 += __uint_as_float(u5 & 0xffff0000u);
            d0 += __uint_as_float(u6 << 16); d1 += __uint_as_float(u6 & 0xffff0000u);
            f0 += __uint_as_float(u7 << 16); f1 += __uint_as_float(u7 & 0xffff0000u);
        }
        for (; e < e1; ++e) {
            uint32 u0 = Hs[(size_t)col[e] * 48 + lane];
            b0 += __uint_as_float(u0 << 16); b1 += __uint_as_float(u0 & 0xffff0000u);
        }
        float di = dinv[node];
        float2 bs = *reinterpret_cast<const float2*>(bias + 2 * lane);
        c0 = ((a0 + b0) + (d0 + f0)) * di + bs.x;
        c1 = ((a1 + b1) + (d1 + f1)) * di + bs.y;
    }

    // LayerNorm over 96 channels: 64-lane butterfly
    float s1 = c0 + c1;
    float s2 = c0 * c0 + c1 * c1;
#pragma unroll
    for (int o = 32; o > 0; o >>= 1) {
        s1 += __shfl_xor(s1, o);
        s2 += __shfl_xor(s2, o);
    }

    if (active) {
        float mu = s1 * (1.f / 96.f);
        float var = s2 * (1.f / 96.f) - mu * mu;
        float rstd = rsqrtf(var + EPS);
        float2 gm = *reinterpret_cast<const float2*>(gamma + 2 * lane);
        float2 bt = *reinterpret_cast<const float2*>(beta + 2 * lane);
        float2 al = *reinterpret_cast<const float2*>(alpha + 2 * lane);
        float ln0 = (c0 - mu) * rstd * gm.x + bt.x;
        float ln1 = (c1 - mu) * rstd * gm.y + bt.y;
        float2 o2;
        o2.x = (ln0 >= 0.f) ? ln0 : al.x * ln0;
        o2.y = (ln1 >= 0.f) ? ln1 : al.y * ln1;
        *reinterpret_cast<float2*>(out + (size_t)node * 96 + 2 * lane) = o2;
    }
}

// ---------------- launch ----------------

extern "C" void kernel_launch(void* const* d_in, const int* in_sizes, int n_in,
                              void* d_out, int out_size, void* d_ws, size_t ws_size,
                              hipStream_t stream) {
    const float* x   = (const float*)d_in[0];
    const int*   ei  = (const int*)d_in[1];
    const float* W1  = (const float*)d_in[2];
    const float* b1  = (const float*)d_in[3];
    const float* W2  = (const float*)d_in[4];
    const float* b2  = (const float*)d_in[5];
    const float* g1  = (const float*)d_in[6];
    const float* be1 = (const float*)d_in[7];
    const float* g2  = (const float*)d_in[8];
    const float* be2 = (const float*)d_in[9];
    const float* a   = (const float*)d_in[10];

    const int N = in_sizes[0] / 128;       // 50000
    const int E = in_sizes[1] / 2;         // 800000
    const int* src = ei;
    const int* dst = ei + E;
    const int nScanBlocks = (N + 255) / 256;   // 196

    char* ws = (char*)d_ws;
    size_t off = 0;
    auto carve = [&](size_t bytes) -> void* {
        void* p = ws + off;
        off += (bytes + 255) & ~(size_t)255;
        return p;
    };
    int*    deg     = (int*)carve((size_t)N * 4);
    int*    cursor  = (int*)carve((size_t)N * 4);
    int*    rowptr  = (int*)carve((size_t)(N + 1) * 4);
    int*    partial = (int*)carve((size_t)N * 4);
    int*    bsum    = (int*)carve((size_t)nScanBlocks * 4);
    float*  dinv    = (float*)carve((size_t)N * 4);
    int*    col     = (int*)carve((size_t)E * 4);
    uint32* hbuf    = (uint32*)carve((size_t)N * 48 * 4);   // bf16x2 table
    float*  p1      = (float*)d_out;   // layer-1 activation reuses output buffer
    float*  outp    = (float*)d_out;

    hipMemsetAsync(deg, 0, (size_t)N * 4, stream);
    hipMemsetAsync(cursor, 0, (size_t)N * 4, stream);

    deg_kernel<<<(E + 255) / 256, 256, 0, stream>>>(dst, deg, E);
    scan_blocks<<<nScanBlocks, 256, 0, stream>>>(deg, partial, bsum, N);
    scan_bsums<<<1, 256, 0, stream>>>(bsum, nScanBlocks);
    finalize_kernel<<<nScanBlocks, 256, 0, stream>>>(partial, bsum, deg, rowptr, dinv, N, E);
    fill_kernel<<<(E + 255) / 256, 256, 0, stream>>>(src, dst, rowptr, cursor, col, E);

    // layer 1
    gemm_kernel<128><<<(N + 63) / 64, 256, 0, stream>>>(x, W1, dinv, hbuf, N);
    agg_ln_prelu<<<(N + 3) / 4, 256, 0, stream>>>(hbuf, dinv, rowptr, col, b1, g1, be1, a, p1, N);
    // layer 2
    gemm_kernel<96><<<(N + 63) / 64, 256, 0, stream>>>(p1, W2, dinv, hbuf, N);
    agg_ln_prelu<<<(N + 3) / 4, 256, 0, stream>>>(hbuf, dinv, rowptr, col, b2, g2, be2, a, outp, N);
}

// Round 5
// 180.442 us; speedup vs baseline: 3.0226x; 1.3871x over previous
//
#include <hip/hip_runtime.h>

#define N_NODES 50000
#define H_DIM 96
#define EPS 1e-5f

typedef unsigned int uint32;
typedef __attribute__((ext_vector_type(8))) short short8;
typedef __attribute__((ext_vector_type(4))) float f32x4;

// ---- bf16 pack helper (RNE) ----
__device__ __forceinline__ uint32 bf16_rne(float f) {
    uint32 b = __float_as_uint(f);
    return (b + 0x7fffu + ((b >> 16) & 1u)) >> 16;
}

// ---------------- CSR build ----------------

// pass 1: degree count + per-edge rank within its dst row (one atomic/edge total)
__global__ void rank_kernel(const int* __restrict__ dst, int* __restrict__ deg,
                            int* __restrict__ rank, int E) {
    int e = blockIdx.x * 256 + threadIdx.x;
    if (e < E) rank[e] = atomicAdd(&deg[dst[e]], 1);
}

// stage 1: per-block exclusive scan (into rowptr) + block sums
__global__ __launch_bounds__(256) void scan_blocks(const int* __restrict__ deg,
                                                   int* __restrict__ rowptr,
                                                   int* __restrict__ bsum, int n) {
    __shared__ int wsum[4];
    int i = blockIdx.x * 256 + threadIdx.x;
    int lane = threadIdx.x & 63, w = threadIdx.x >> 6;
    int v = (i < n) ? deg[i] : 0;
    int s = v;
#pragma unroll
    for (int o = 1; o < 64; o <<= 1) { int t = __shfl_up(s, o); if (lane >= o) s += t; }
    if (lane == 63) wsum[w] = s;
    __syncthreads();
    int off = 0;
#pragma unroll
    for (int k = 0; k < 4; ++k) if (k < w) off += wsum[k];
    s += off;
    if (i < n) rowptr[i] = s - v;               // exclusive within block
    if (threadIdx.x == 255) bsum[blockIdx.x] = s;
}

// stage 2: single-block exclusive scan of block sums (nb <= 256)
__global__ __launch_bounds__(256) void scan_bsums(int* __restrict__ bsum, int nb) {
    __shared__ int wsum[4];
    int t = threadIdx.x;
    int lane = t & 63, w = t >> 6;
    int v = (t < nb) ? bsum[t] : 0;
    int s = v;
#pragma unroll
    for (int o = 1; o < 64; o <<= 1) { int tt = __shfl_up(s, o); if (lane >= o) s += tt; }
    if (lane == 63) wsum[w] = s;
    __syncthreads();
    int off = 0;
#pragma unroll
    for (int k = 0; k < 4; ++k) if (k < w) off += wsum[k];
    s += off;
    if (t < nb) bsum[t] = s - v;
}

// stage 3: rowptr += block offset; fused dinv
__global__ __launch_bounds__(256) void finalize_kernel(int* __restrict__ rowptr,
                                                       const int* __restrict__ bsum,
                                                       const int* __restrict__ deg,
                                                       float* __restrict__ dinv,
                                                       int n, int E) {
    int i = blockIdx.x * 256 + threadIdx.x;
    if (i < n) {
        rowptr[i] += bsum[blockIdx.x];
        dinv[i] = rsqrtf((float)(deg[i] + 1));  // +1 = self loop
    }
    if (i == 0) rowptr[n] = E;
}

// pass 2: pure scatter, no atomics
__global__ void fill_kernel(const int* __restrict__ src, const int* __restrict__ dst,
                            const int* __restrict__ rank, const int* __restrict__ rowptr,
                            int* __restrict__ col, int E) {
    int e = blockIdx.x * 256 + threadIdx.x;
    if (e < E) col[rowptr[dst[e]] + rank[e]] = src[e];
}

// ---- W prep: Bt[n][k] = bf16(W[k][n]), rows padded to KP = K+8 bf16 ----
__global__ void wprep_kernel(const float* __restrict__ W, uint32* __restrict__ Bt,
                             int K, int KP2) {
    int idx = blockIdx.x * 256 + threadIdx.x;
    int kh = K >> 1;
    if (idx < 96 * kh) {
        int n = idx / kh, i = idx % kh;
        float v0 = W[(size_t)(2 * i) * 96 + n];
        float v1 = W[(size_t)(2 * i + 1) * 96 + n];
        Bt[n * KP2 + i] = bf16_rne(v0) | (bf16_rne(v1) << 16);
    }
}

// ---- MFMA GEMM: Hs[row] = bf16x2-packed (A @ W) * dinv[row] ----
// A: f32 [N][K] (AF32) or bf16x2 [N][K/2] uints. Bt: [96][KP] bf16 pre-packed.
// Block: 64 rows x 96 cols, 4 waves (16 rows each), full K in LDS.

template <int K, bool AF32>
__global__ __launch_bounds__(256) void gemm_mfma(const void* __restrict__ Aptr,
                                                 const uint32* __restrict__ Bt,
                                                 const float* __restrict__ dinv,
                                                 uint32* __restrict__ Hs, int N) {
    constexpr int KP2 = (K + 8) / 2;          // uints per padded row (68 / 52)
    __shared__ uint32 As[64 * KP2];
    __shared__ uint32 Bs[96 * KP2];
    int tid = threadIdx.x;
    int rowbase = blockIdx.x * 64;

    if constexpr (AF32) {
        const float* A = (const float*)Aptr;
        for (int f = tid; f < 64 * (K / 4); f += 256) {
            int r = f / (K / 4), q = f % (K / 4);
            int row = rowbase + r;
            float4 v = make_float4(0.f, 0.f, 0.f, 0.f);
            if (row < N) v = *reinterpret_cast<const float4*>(A + (size_t)row * K + q * 4);
            As[r * KP2 + q * 2]     = bf16_rne(v.x) | (bf16_rne(v.y) << 16);
            As[r * KP2 + q * 2 + 1] = bf16_rne(v.z) | (bf16_rne(v.w) << 16);
        }
    } else {
        const uint32* A = (const uint32*)Aptr;
        for (int f = tid; f < 64 * (K / 8); f += 256) {
            int r = f / (K / 8), s = f % (K / 8);
            int row = rowbase + r;
            uint4 v = make_uint4(0, 0, 0, 0);
            if (row < N) v = *reinterpret_cast<const uint4*>(A + (size_t)row * (K / 2) + s * 4);
            *reinterpret_cast<uint4*>(&As[r * KP2 + s * 4]) = v;
        }
    }
    for (int f = tid; f < 96 * KP2 / 4; f += 256) {
        *reinterpret_cast<uint4*>(&Bs[f * 4]) = *reinterpret_cast<const uint4*>(Bt + f * 4);
    }
    __syncthreads();

    int l = tid & 63, w = tid >> 6;
    int l15 = l & 15, lq = l >> 4;

    f32x4 acc[6];
#pragma unroll
    for (int j = 0; j < 6; ++j) acc[j] = (f32x4){0.f, 0.f, 0.f, 0.f};

    const uint32* arow = &As[(w * 16 + l15) * KP2 + lq * 4];   // k = lq*8
#pragma unroll
    for (int kc = 0; kc < K / 32; ++kc) {
        short8 a = *reinterpret_cast<const short8*>(arow + kc * 16);
#pragma unroll
        for (int j = 0; j < 6; ++j) {
            short8 b = *reinterpret_cast<const short8*>(&Bs[(j * 16 + l15) * KP2 + lq * 4 + kc * 16]);
            acc[j] = __builtin_amdgcn_mfma_f32_16x16x32_bf16(a, b, acc[j], 0, 0, 0);
        }
    }

    // epilogue: scale by dinv, pack bf16x2 (cols live in lane&15; pair via shfl_xor 1)
#pragma unroll
    for (int r = 0; r < 4; ++r) {
        int row = rowbase + w * 16 + lq * 4 + r;
        float di = (row < N) ? dinv[row] : 0.f;
#pragma unroll
        for (int j = 0; j < 6; ++j) {
            float v = acc[j][r] * di;
            float vp = __shfl_xor(v, 1);
            if (row < N && !(l & 1)) {
                Hs[(size_t)row * 48 + (j * 16 + l15) / 2] = bf16_rne(v) | (bf16_rne(vp) << 16);
            }
        }
    }
}

// ---------- fused: aggregate (sym-norm) + bias + LayerNorm + PReLU ----------
// One wave per node; lanes 0..47 each own 2 channels (bf16x2).
// PACK_OUT: write bf16x2 table (layer-1 activation) instead of f32.

template <bool PACK_OUT>
__global__ __launch_bounds__(256) void agg_ln_prelu(const uint32* __restrict__ Hs,
                                                    const float* __restrict__ dinv,
                                                    const int* __restrict__ rowptr,
                                                    const int* __restrict__ col,
                                                    const float* __restrict__ bias,
                                                    const float* __restrict__ gamma,
                                                    const float* __restrict__ beta,
                                                    const float* __restrict__ alpha,
                                                    void* __restrict__ outv, int N) {
    int lane = threadIdx.x & 63;
    int node = blockIdx.x * 4 + (threadIdx.x >> 6);
    if (node >= N) return;

    bool active = lane < 48;
    float c0 = 0.f, c1 = 0.f;

    if (active) {
        uint32 u = Hs[(size_t)node * 48 + lane];
        float a0 = __uint_as_float(u << 16), a1 = __uint_as_float(u & 0xffff0000u);
        float b0 = 0.f, b1 = 0.f, d0 = 0.f, d1 = 0.f, f0 = 0.f, f1 = 0.f;
        int e0 = rowptr[node], e1 = rowptr[node + 1];
        int e = e0;
        for (; e + 8 <= e1; e += 8) {
            int j0 = col[e],     j1 = col[e + 1], j2 = col[e + 2], j3 = col[e + 3];
            int j4 = col[e + 4], j5 = col[e + 5], j6 = col[e + 6], j7 = col[e + 7];
            uint32 u0 = Hs[(size_t)j0 * 48 + lane];
            uint32 u1 = Hs[(size_t)j1 * 48 + lane];
            uint32 u2 = Hs[(size_t)j2 * 48 + lane];
            uint32 u3 = Hs[(size_t)j3 * 48 + lane];
            uint32 u4 = Hs[(size_t)j4 * 48 + lane];
            uint32 u5 = Hs[(size_t)j5 * 48 + lane];
            uint32 u6 = Hs[(size_t)j6 * 48 + lane];
            uint32 u7 = Hs[(size_t)j7 * 48 + lane];
            a0 += __uint_as_float(u0 << 16); a1 += __uint_as_float(u0 & 0xffff0000u);
            b0 += __uint_as_float(u1 << 16); b1 += __uint_as_float(u1 & 0xffff0000u);
            d0 += __uint_as_float(u2 << 16); d1 += __uint_as_float(u2 & 0xffff0000u);
            f0 += __uint_as_float(u3 << 16); f1 += __uint_as_float(u3 & 0xffff0000u);
            a0 += __uint_as_float(u4 << 16); a1 += __uint_as_float(u4 & 0xffff0000u);
            b0 += __uint_as_float(u5 << 16); b1 += __uint_as_float(u5 & 0xffff0000u);
            d0 += __uint_as_float(u6 << 16); d1 += __uint_as_float(u6 & 0xffff0000u);
            f0 += __uint_as_float(u7 << 16); f1 += __uint_as_float(u7 & 0xffff0000u);
        }
        for (; e < e1; ++e) {
            uint32 u0 = Hs[(size_t)col[e] * 48 + lane];
            b0 += __uint_as_float(u0 << 16); b1 += __uint_as_float(u0 & 0xffff0000u);
        }
        float di = dinv[node];
        float2 bs = *reinterpret_cast<const float2*>(bias + 2 * lane);
        c0 = ((a0 + b0) + (d0 + f0)) * di + bs.x;
        c1 = ((a1 + b1) + (d1 + f1)) * di + bs.y;
    }

    float s1 = c0 + c1;
    float s2 = c0 * c0 + c1 * c1;
#pragma unroll
    for (int o = 32; o > 0; o >>= 1) {
        s1 += __shfl_xor(s1, o);
        s2 += __shfl_xor(s2, o);
    }

    if (active) {
        float mu = s1 * (1.f / 96.f);
        float var = s2 * (1.f / 96.f) - mu * mu;
        float rstd = rsqrtf(var + EPS);
        float2 gm = *reinterpret_cast<const float2*>(gamma + 2 * lane);
        float2 bt = *reinterpret_cast<const float2*>(beta + 2 * lane);
        float2 al = *reinterpret_cast<const float2*>(alpha + 2 * lane);
        float ln0 = (c0 - mu) * rstd * gm.x + bt.x;
        float ln1 = (c1 - mu) * rstd * gm.y + bt.y;
        float o0 = (ln0 >= 0.f) ? ln0 : al.x * ln0;
        float o1 = (ln1 >= 0.f) ? ln1 : al.y * ln1;
        if constexpr (PACK_OUT) {
            ((uint32*)outv)[(size_t)node * 48 + lane] = bf16_rne(o0) | (bf16_rne(o1) << 16);
        } else {
            float2 o2; o2.x = o0; o2.y = o1;
            *reinterpret_cast<float2*>((float*)outv + (size_t)node * 96 + 2 * lane) = o2;
        }
    }
}

// ---------------- launch ----------------

extern "C" void kernel_launch(void* const* d_in, const int* in_sizes, int n_in,
                              void* d_out, int out_size, void* d_ws, size_t ws_size,
                              hipStream_t stream) {
    const float* x   = (const float*)d_in[0];
    const int*   ei  = (const int*)d_in[1];
    const float* W1  = (const float*)d_in[2];
    const float* b1  = (const float*)d_in[3];
    const float* W2  = (const float*)d_in[4];
    const float* b2  = (const float*)d_in[5];
    const float* g1  = (const float*)d_in[6];
    const float* be1 = (const float*)d_in[7];
    const float* g2  = (const float*)d_in[8];
    const float* be2 = (const float*)d_in[9];
    const float* a   = (const float*)d_in[10];

    const int N = in_sizes[0] / 128;       // 50000
    const int E = in_sizes[1] / 2;         // 800000
    const int* src = ei;
    const int* dst = ei + E;
    const int nScanBlocks = (N + 255) / 256;

    char* ws = (char*)d_ws;
    size_t off = 0;
    auto carve = [&](size_t bytes) -> void* {
        void* p = ws + off;
        off += (bytes + 255) & ~(size_t)255;
        return p;
    };
    int*    deg    = (int*)carve((size_t)N * 4);
    int*    rowptr = (int*)carve((size_t)(N + 1) * 4);
    int*    bsum   = (int*)carve((size_t)nScanBlocks * 4);
    float*  dinv   = (float*)carve((size_t)N * 4);
    int*    rank   = (int*)carve((size_t)E * 4);
    int*    col    = (int*)carve((size_t)E * 4);
    uint32* hbuf   = (uint32*)carve((size_t)N * 48 * 4);   // bf16x2 gather table
    uint32* w1bt   = (uint32*)carve((size_t)96 * 68 * 4);  // W1^T bf16 padded [96][136]
    uint32* w2bt   = (uint32*)carve((size_t)96 * 52 * 4);  // W2^T bf16 padded [96][104]
    uint32* p1     = (uint32*)d_out;   // layer-1 bf16x2 activations (front of d_out)
    float*  outp   = (float*)d_out;

    hipMemsetAsync(deg, 0, (size_t)N * 4, stream);

    rank_kernel<<<(E + 255) / 256, 256, 0, stream>>>(dst, deg, rank, E);
    scan_blocks<<<nScanBlocks, 256, 0, stream>>>(deg, rowptr, bsum, N);
    scan_bsums<<<1, 256, 0, stream>>>(bsum, nScanBlocks);
    finalize_kernel<<<nScanBlocks, 256, 0, stream>>>(rowptr, bsum, deg, dinv, N, E);
    fill_kernel<<<(E + 255) / 256, 256, 0, stream>>>(src, dst, rank, rowptr, col, E);

    wprep_kernel<<<(96 * 64 + 255) / 256, 256, 0, stream>>>(W1, w1bt, 128, 68);
    wprep_kernel<<<(96 * 48 + 255) / 256, 256, 0, stream>>>(W2, w2bt, 96, 52);

    // layer 1
    gemm_mfma<128, true><<<(N + 63) / 64, 256, 0, stream>>>(x, w1bt, dinv, hbuf, N);
    agg_ln_prelu<true><<<(N + 3) / 4, 256, 0, stream>>>(hbuf, dinv, rowptr, col, b1, g1, be1, a, p1, N);
    // layer 2
    gemm_mfma<96, false><<<(N + 63) / 64, 256, 0, stream>>>(p1, w2bt, dinv, hbuf, N);
    agg_ln_prelu<false><<<(N + 3) / 4, 256, 0, stream>>>(hbuf, dinv, rowptr, col, b2, g2, be2, a, outp, N);
}

// Round 6
// 152.925 us; speedup vs baseline: 3.5665x; 1.1799x over previous
//
#include <hip/hip_runtime.h>

#define N_NODES 50000
#define H_DIM 96
#define EPS 1e-5f

typedef unsigned int uint32;
typedef __attribute__((ext_vector_type(8))) short short8;
typedef __attribute__((ext_vector_type(4))) float f32x4;

// ---- bf16 pack helper (RNE) ----
__device__ __forceinline__ uint32 bf16_rne(float f) {
    uint32 b = __float_as_uint(f);
    return (b + 0x7fffu + ((b >> 16) & 1u)) >> 16;
}

// ---------------- CSR build ----------------

__global__ void zero_kernel(int* __restrict__ p, int n) {
    int i = blockIdx.x * 256 + threadIdx.x;
    if (i < n) p[i] = 0;
}

// pass 1: degree count + per-edge rank within its dst row (one atomic/edge total)
__global__ void rank_kernel(const int* __restrict__ dst, int* __restrict__ deg,
                            int* __restrict__ rank, int E) {
    int e = blockIdx.x * 256 + threadIdx.x;
    if (e < E) rank[e] = atomicAdd(&deg[dst[e]], 1);
}

// stage 1: per-block exclusive scan (into rowptr) + block sums
__global__ __launch_bounds__(256) void scan_blocks(const int* __restrict__ deg,
                                                   int* __restrict__ rowptr,
                                                   int* __restrict__ bsum, int n) {
    __shared__ int wsum[4];
    int i = blockIdx.x * 256 + threadIdx.x;
    int lane = threadIdx.x & 63, w = threadIdx.x >> 6;
    int v = (i < n) ? deg[i] : 0;
    int s = v;
#pragma unroll
    for (int o = 1; o < 64; o <<= 1) { int t = __shfl_up(s, o); if (lane >= o) s += t; }
    if (lane == 63) wsum[w] = s;
    __syncthreads();
    int off = 0;
#pragma unroll
    for (int k = 0; k < 4; ++k) if (k < w) off += wsum[k];
    s += off;
    if (i < n) rowptr[i] = s - v;               // exclusive within block
    if (threadIdx.x == 255) bsum[blockIdx.x] = s;
}

// stage 2: single-block exclusive scan of block sums (nb <= 256)
__global__ __launch_bounds__(256) void scan_bsums(int* __restrict__ bsum, int nb) {
    __shared__ int wsum[4];
    int t = threadIdx.x;
    int lane = t & 63, w = t >> 6;
    int v = (t < nb) ? bsum[t] : 0;
    int s = v;
#pragma unroll
    for (int o = 1; o < 64; o <<= 1) { int tt = __shfl_up(s, o); if (lane >= o) s += tt; }
    if (lane == 63) wsum[w] = s;
    __syncthreads();
    int off = 0;
#pragma unroll
    for (int k = 0; k < 4; ++k) if (k < w) off += wsum[k];
    s += off;
    if (t < nb) bsum[t] = s - v;
}

// stage 3: rowptr += block offset; fused dinv
__global__ __launch_bounds__(256) void finalize_kernel(int* __restrict__ rowptr,
                                                       const int* __restrict__ bsum,
                                                       const int* __restrict__ deg,
                                                       float* __restrict__ dinv,
                                                       int n, int E) {
    int i = blockIdx.x * 256 + threadIdx.x;
    if (i < n) {
        rowptr[i] += bsum[blockIdx.x];
        dinv[i] = rsqrtf((float)(deg[i] + 1));  // +1 = self loop
    }
    if (i == 0) rowptr[n] = E;
}

// pass 2: pure scatter, no atomics
__global__ void fill_kernel(const int* __restrict__ src, const int* __restrict__ dst,
                            const int* __restrict__ rank, const int* __restrict__ rowptr,
                            int* __restrict__ col, int E) {
    int e = blockIdx.x * 256 + threadIdx.x;
    if (e < E) col[rowptr[dst[e]] + rank[e]] = src[e];
}

// ---- W prep (both layers fused): Bt[n][k] = bf16(W[k][n]), rows padded ----
__global__ void wprep2_kernel(const float* __restrict__ W1, uint32* __restrict__ B1,
                              const float* __restrict__ W2, uint32* __restrict__ B2) {
    int idx = blockIdx.x * 256 + threadIdx.x;
    if (idx < 96 * 64) {                      // W1: K=128, KP2=68
        int n = idx / 64, i = idx % 64;
        float v0 = W1[(size_t)(2 * i) * 96 + n];
        float v1 = W1[(size_t)(2 * i + 1) * 96 + n];
        B1[n * 68 + i] = bf16_rne(v0) | (bf16_rne(v1) << 16);
    } else if (idx < 96 * 64 + 96 * 48) {     // W2: K=96, KP2=52
        int t = idx - 96 * 64;
        int n = t / 48, i = t % 48;
        float v0 = W2[(size_t)(2 * i) * 96 + n];
        float v1 = W2[(size_t)(2 * i + 1) * 96 + n];
        B2[n * 52 + i] = bf16_rne(v0) | (bf16_rne(v1) << 16);
    }
}

// ---- MFMA GEMM: Hs[row] = bf16x2-packed (A @ W) * dinv[row] ----

template <int K, bool AF32>
__global__ __launch_bounds__(256) void gemm_mfma(const void* __restrict__ Aptr,
                                                 const uint32* __restrict__ Bt,
                                                 const float* __restrict__ dinv,
                                                 uint32* __restrict__ Hs, int N) {
    constexpr int KP2 = (K + 8) / 2;          // uints per padded row (68 / 52)
    __shared__ uint32 As[64 * KP2];
    __shared__ uint32 Bs[96 * KP2];
    int tid = threadIdx.x;
    int rowbase = blockIdx.x * 64;

    if constexpr (AF32) {
        const float* A = (const float*)Aptr;
        for (int f = tid; f < 64 * (K / 4); f += 256) {
            int r = f / (K / 4), q = f % (K / 4);
            int row = rowbase + r;
            float4 v = make_float4(0.f, 0.f, 0.f, 0.f);
            if (row < N) v = *reinterpret_cast<const float4*>(A + (size_t)row * K + q * 4);
            As[r * KP2 + q * 2]     = bf16_rne(v.x) | (bf16_rne(v.y) << 16);
            As[r * KP2 + q * 2 + 1] = bf16_rne(v.z) | (bf16_rne(v.w) << 16);
        }
    } else {
        const uint32* A = (const uint32*)Aptr;
        for (int f = tid; f < 64 * (K / 8); f += 256) {
            int r = f / (K / 8), s = f % (K / 8);
            int row = rowbase + r;
            uint4 v = make_uint4(0, 0, 0, 0);
            if (row < N) v = *reinterpret_cast<const uint4*>(A + (size_t)row * (K / 2) + s * 4);
            *reinterpret_cast<uint4*>(&As[r * KP2 + s * 4]) = v;
        }
    }
    for (int f = tid; f < 96 * KP2 / 4; f += 256) {
        *reinterpret_cast<uint4*>(&Bs[f * 4]) = *reinterpret_cast<const uint4*>(Bt + f * 4);
    }
    __syncthreads();

    int l = tid & 63, w = tid >> 6;
    int l15 = l & 15, lq = l >> 4;

    f32x4 acc[6];
#pragma unroll
    for (int j = 0; j < 6; ++j) acc[j] = (f32x4){0.f, 0.f, 0.f, 0.f};

    const uint32* arow = &As[(w * 16 + l15) * KP2 + lq * 4];   // k = lq*8
#pragma unroll
    for (int kc = 0; kc < K / 32; ++kc) {
        short8 a = *reinterpret_cast<const short8*>(arow + kc * 16);
#pragma unroll
        for (int j = 0; j < 6; ++j) {
            short8 b = *reinterpret_cast<const short8*>(&Bs[(j * 16 + l15) * KP2 + lq * 4 + kc * 16]);
            acc[j] = __builtin_amdgcn_mfma_f32_16x16x32_bf16(a, b, acc[j], 0, 0, 0);
        }
    }

#pragma unroll
    for (int r = 0; r < 4; ++r) {
        int row = rowbase + w * 16 + lq * 4 + r;
        float di = (row < N) ? dinv[row] : 0.f;
#pragma unroll
        for (int j = 0; j < 6; ++j) {
            float v = acc[j][r] * di;
            float vp = __shfl_xor(v, 1);
            if (row < N && !(l & 1)) {
                Hs[(size_t)row * 48 + (j * 16 + l15) / 2] = bf16_rne(v) | (bf16_rne(vp) << 16);
            }
        }
    }
}

// ---------- fused: aggregate (sym-norm) + bias + LayerNorm + PReLU ----------
// One wave per node; lanes 0..47 each own 2 channels (bf16x2).
// Wave-uniform scalars (node, rowptr, col values) forced to SGPRs.

template <bool PACK_OUT>
__global__ __launch_bounds__(256) void agg_ln_prelu(const uint32* __restrict__ Hs,
                                                    const float* __restrict__ dinv,
                                                    const int* __restrict__ rowptr,
                                                    const int* __restrict__ col,
                                                    const float* __restrict__ bias,
                                                    const float* __restrict__ gamma,
                                                    const float* __restrict__ beta,
                                                    const float* __restrict__ alpha,
                                                    void* __restrict__ outv, int N) {
    int lane = threadIdx.x & 63;
    int node = blockIdx.x * 4 + (threadIdx.x >> 6);
    if (node >= N) return;

    bool active = lane < 48;
    float c0 = 0.f, c1 = 0.f;

    if (active) {
        const uint32* hl = Hs + lane;
        int e0 = __builtin_amdgcn_readfirstlane(rowptr[node]);
        int e1 = __builtin_amdgcn_readfirstlane(rowptr[node + 1]);

        uint32 us = hl[(size_t)node * 48];      // self loop (pre-scaled)
        float pa0 = __uint_as_float(us << 16), pb0 = __uint_as_float(us & 0xffff0000u);
        float pa1 = 0.f, pb1 = 0.f, pa2 = 0.f, pb2 = 0.f, pa3 = 0.f, pb3 = 0.f;

        int e = e0;
        // 16 gathers in flight (avg degree = 16)
        for (; e + 16 <= e1; e += 16) {
            uint32 u[16];
#pragma unroll
            for (int t = 0; t < 16; ++t) {
                int j = __builtin_amdgcn_readfirstlane(col[e + t]);
                u[t] = hl[(size_t)j * 48];
            }
#pragma unroll
            for (int t = 0; t < 16; ++t) {
                float lo = __uint_as_float(u[t] << 16);
                float hi = __uint_as_float(u[t] & 0xffff0000u);
                switch (t & 3) {
                    case 0: pa0 += lo; pb0 += hi; break;
                    case 1: pa1 += lo; pb1 += hi; break;
                    case 2: pa2 += lo; pb2 += hi; break;
                    default: pa3 += lo; pb3 += hi; break;
                }
            }
        }
        // clamped 8-wide tail (duplicate loads masked to zero)
        for (; e < e1; e += 8) {
            uint32 u[8];
#pragma unroll
            for (int t = 0; t < 8; ++t) {
                int ee = min(e + t, e1 - 1);
                int j = __builtin_amdgcn_readfirstlane(col[ee]);
                u[t] = hl[(size_t)j * 48];
                if (e + t >= e1) u[t] = 0u;
            }
#pragma unroll
            for (int t = 0; t < 8; ++t) {
                float lo = __uint_as_float(u[t] << 16);
                float hi = __uint_as_float(u[t] & 0xffff0000u);
                switch (t & 3) {
                    case 0: pa0 += lo; pb0 += hi; break;
                    case 1: pa1 += lo; pb1 += hi; break;
                    case 2: pa2 += lo; pb2 += hi; break;
                    default: pa3 += lo; pb3 += hi; break;
                }
            }
        }

        float di = dinv[node];
        float2 bs = *reinterpret_cast<const float2*>(bias + 2 * lane);
        c0 = ((pa0 + pa1) + (pa2 + pa3)) * di + bs.x;
        c1 = ((pb0 + pb1) + (pb2 + pb3)) * di + bs.y;
    }

    // LayerNorm over 96 channels: 64-lane butterfly
    float s1 = c0 + c1;
    float s2 = c0 * c0 + c1 * c1;
#pragma unroll
    for (int o = 32; o > 0; o >>= 1) {
        s1 += __shfl_xor(s1, o);
        s2 += __shfl_xor(s2, o);
    }

    if (active) {
        float mu = s1 * (1.f / 96.f);
        float var = s2 * (1.f / 96.f) - mu * mu;
        float rstd = rsqrtf(var + EPS);
        float2 gm = *reinterpret_cast<const float2*>(gamma + 2 * lane);
        float2 bt = *reinterpret_cast<const float2*>(beta + 2 * lane);
        float2 al = *reinterpret_cast<const float2*>(alpha + 2 * lane);
        float ln0 = (c0 - mu) * rstd * gm.x + bt.x;
        float ln1 = (c1 - mu) * rstd * gm.y + bt.y;
        float o0 = (ln0 >= 0.f) ? ln0 : al.x * ln0;
        float o1 = (ln1 >= 0.f) ? ln1 : al.y * ln1;
        if constexpr (PACK_OUT) {
            ((uint32*)outv)[(size_t)node * 48 + lane] = bf16_rne(o0) | (bf16_rne(o1) << 16);
        } else {
            float2 o2; o2.x = o0; o2.y = o1;
            *reinterpret_cast<float2*>((float*)outv + (size_t)node * 96 + 2 * lane) = o2;
        }
    }
}

// ---------------- launch ----------------

extern "C" void kernel_launch(void* const* d_in, const int* in_sizes, int n_in,
                              void* d_out, int out_size, void* d_ws, size_t ws_size,
                              hipStream_t stream) {
    const float* x   = (const float*)d_in[0];
    const int*   ei  = (const int*)d_in[1];
    const float* W1  = (const float*)d_in[2];
    const float* b1  = (const float*)d_in[3];
    const float* W2  = (const float*)d_in[4];
    const float* b2  = (const float*)d_in[5];
    const float* g1  = (const float*)d_in[6];
    const float* be1 = (const float*)d_in[7];
    const float* g2  = (const float*)d_in[8];
    const float* be2 = (const float*)d_in[9];
    const float* a   = (const float*)d_in[10];

    const int N = in_sizes[0] / 128;       // 50000
    const int E = in_sizes[1] / 2;         // 800000
    const int* src = ei;
    const int* dst = ei + E;
    const int nScanBlocks = (N + 255) / 256;

    char* ws = (char*)d_ws;
    size_t off = 0;
    auto carve = [&](size_t bytes) -> void* {
        void* p = ws + off;
        off += (bytes + 255) & ~(size_t)255;
        return p;
    };
    int*    deg    = (int*)carve((size_t)N * 4);
    int*    rowptr = (int*)carve((size_t)(N + 1) * 4);
    int*    bsum   = (int*)carve((size_t)nScanBlocks * 4);
    float*  dinv   = (float*)carve((size_t)N * 4);
    int*    rank   = (int*)carve((size_t)E * 4);
    int*    col    = (int*)carve((size_t)E * 4);
    uint32* hbuf   = (uint32*)carve((size_t)N * 48 * 4);   // bf16x2 gather table
    uint32* w1bt   = (uint32*)carve((size_t)96 * 68 * 4);  // W1^T bf16 padded
    uint32* w2bt   = (uint32*)carve((size_t)96 * 52 * 4);  // W2^T bf16 padded
    uint32* p1     = (uint32*)d_out;   // layer-1 bf16x2 activations (front of d_out)
    float*  outp   = (float*)d_out;

    zero_kernel<<<nScanBlocks, 256, 0, stream>>>(deg, N);
    rank_kernel<<<(E + 255) / 256, 256, 0, stream>>>(dst, deg, rank, E);
    scan_blocks<<<nScanBlocks, 256, 0, stream>>>(deg, rowptr, bsum, N);
    scan_bsums<<<1, 256, 0, stream>>>(bsum, nScanBlocks);
    finalize_kernel<<<nScanBlocks, 256, 0, stream>>>(rowptr, bsum, deg, dinv, N, E);
    fill_kernel<<<(E + 255) / 256, 256, 0, stream>>>(src, dst, rank, rowptr, col, E);

    wprep2_kernel<<<(96 * 64 + 96 * 48 + 255) / 256, 256, 0, stream>>>(W1, w1bt, W2, w2bt);

    // layer 1
    gemm_mfma<128, true><<<(N + 63) / 64, 256, 0, stream>>>(x, w1bt, dinv, hbuf, N);
    agg_ln_prelu<true><<<(N + 3) / 4, 256, 0, stream>>>(hbuf, dinv, rowptr, col, b1, g1, be1, a, p1, N);
    // layer 2
    gemm_mfma<96, false><<<(N + 63) / 64, 256, 0, stream>>>(p1, w2bt, dinv, hbuf, N);
    agg_ln_prelu<false><<<(N + 3) / 4, 256, 0, stream>>>(hbuf, dinv, rowptr, col, b2, g2, be2, a, outp, N);
}